// Round 4
// baseline (412.425 us; speedup 1.0000x reference)
//
#include <hip/hip_runtime.h>

#define T_TOK 2048
#define DIM   2048
#define NEXP  8
#define FF    768
#define NGRP  16   // (expert, slot)

typedef unsigned short u16;
typedef unsigned int   u32;
typedef __bf16 bf16x8 __attribute__((ext_vector_type(8)));
typedef float  f32x4  __attribute__((ext_vector_type(4)));
typedef u16    u16x4  __attribute__((ext_vector_type(4)));
typedef u16    u16x8  __attribute__((ext_vector_type(8)));

#define AS1 __attribute__((address_space(1)))
#define AS3 __attribute__((address_space(3)))

__device__ __forceinline__ u16 f2bf(float f) {
    union { u32 i; float f; } v; v.f = f;
    u32 r = v.i + 0x7FFF + ((v.i >> 16) & 1);   // round-to-nearest-even
    return (u16)(r >> 16);
}
__device__ __forceinline__ float bf2f(u16 u) {
    union { u32 i; float f; } v; v.i = ((u32)u) << 16; return v.f;
}

// async global->LDS, 16B per lane; LDS dest = wave-uniform base + lane*16
__device__ __forceinline__ void gload16(const u16* g, u16* l) {
    __builtin_amdgcn_global_load_lds((const AS1 u32*)g, (AS3 u32*)l, 16, 0, 0);
}

// ---------------- fused fp32 -> bf16 bulk convert (4 tensors) ----------------
__global__ void cvt4_kernel(const float* __restrict__ s0, u16* __restrict__ d0, int n0,
                            const float* __restrict__ s1, u16* __restrict__ d1, int n1,
                            const float* __restrict__ s2, u16* __restrict__ d2, int n2,
                            const float* __restrict__ s3, u16* __restrict__ d3, int n3) {
    const float* s; u16* d; int n4;
    switch (blockIdx.y) {
        case 0: s = s0; d = d0; n4 = n0; break;
        case 1: s = s1; d = d1; n4 = n1; break;
        case 2: s = s2; d = d2; n4 = n2; break;
        default: s = s3; d = d3; n4 = n3; break;
    }
    int i = blockIdx.x * blockDim.x + threadIdx.x;
    int st = gridDim.x * blockDim.x;
    for (; i < n4; i += st) {
        f32x4 v = ((const f32x4*)s)[i];
        u16x4 o;
#pragma unroll
        for (int j = 0; j < 4; j++) o[j] = f2bf(v[j]);
        ((u16x4*)d)[i] = o;
    }
}

// ---------------- Router: scores, top-2, softmax, group counts ----------------
__global__ void router_kernel(const float* __restrict__ x, const float* __restrict__ wr,
                              int* cnt, int* rt_e, float* rt_p) {
    int t = blockIdx.x;
    int lane = threadIdx.x;
    float xv[32];
#pragma unroll
    for (int i = 0; i < 32; i++) xv[i] = x[(size_t)t * DIM + i * 64 + lane];
    float s[NEXP];
#pragma unroll
    for (int e = 0; e < NEXP; e++) {
        float acc = 0.f;
#pragma unroll
        for (int i = 0; i < 32; i++) acc += xv[i] * wr[(size_t)e * DIM + i * 64 + lane];
        for (int off = 32; off; off >>= 1) acc += __shfl_xor(acc, off);
        s[e] = acc;
    }
    if (lane == 0) {
        int bi = 0; float bv = s[0];
        for (int e = 1; e < NEXP; e++) if (s[e] > bv) { bv = s[e]; bi = e; }
        float sv = -1e30f; int si = 0;
        for (int e = 0; e < NEXP; e++) { if (e == bi) continue; if (s[e] > sv) { sv = s[e]; si = e; } }
        float p0 = 1.f / (1.f + __expf(sv - bv));
        float p1 = 1.f - p0;
        rt_e[t * 2 + 0] = bi; rt_e[t * 2 + 1] = si;
        rt_p[t * 2 + 0] = p0; rt_p[t * 2 + 1] = p1;
        atomicAdd(&cnt[bi * 2 + 0], 1);
        atomicAdd(&cnt[si * 2 + 1], 1);
    }
}

// ---------------- Scan: bases + 128-row tile worklist ----------------
__global__ void scan_kernel(const int* cnt, int* base, int* tile_g, int* tile_m0, int* ntiles) {
    if (threadIdx.x == 0 && blockIdx.x == 0) {
        int off = 0, nt = 0;
        for (int g = 0; g < NGRP; g++) {
            base[g] = off;
            int c = cnt[g];
            for (int m0 = 0; m0 < c; m0 += 128) { tile_g[nt] = g; tile_m0[nt] = m0; nt++; }
            off += c;
        }
        *ntiles = nt;
    }
}

// ---------------- Assign: compact row -> (token, prob) ----------------
__global__ void assign_kernel(const int* rt_e, const float* rt_p, const int* base,
                              int* poscnt, int* rowtok, float* rowprob) {
    int t = blockIdx.x * blockDim.x + threadIdx.x;
    if (t >= T_TOK) return;
    for (int k = 0; k < 2; k++) {
        int g = rt_e[t * 2 + k] * 2 + k;
        int pos = atomicAdd(&poscnt[g], 1);
        int row = base[g] + pos;
        rowtok[row] = t;
        rowprob[row] = rt_p[t * 2 + k];
    }
}

// ---------------- Gate/Up GEMM + SiLU: 128 rows x 64 f (N=128 G|U interleaved), BK=64 ----------------
__launch_bounds__(256)
__global__ void gateup_kernel(const u16* __restrict__ xb, const u16* __restrict__ wgb,
                              const u16* __restrict__ wub,
                              const int* cnt, const int* base, const int* tile_g,
                              const int* tile_m0, const int* ntiles,
                              const int* rowtok, const float* rowprob,
                              u16* __restrict__ hidden) {
    int tile = blockIdx.x;
    if (tile >= *ntiles) return;
    int g = tile_g[tile], m0 = tile_m0[tile];
    int e = g >> 1;
    int f0 = blockIdx.y * 64;
    int cg = cnt[g], bg_ = base[g];

    __shared__ u16 As[128 * 64];
    __shared__ u16 Bs[128 * 64];
    __shared__ int   tks[128];
    __shared__ float ps[128];

    int tid = threadIdx.x;
    if (tid < 128) {
        int valid = (m0 + tid) < cg;
        tks[tid] = valid ? rowtok[bg_ + m0 + tid] : 0;
        ps[tid]  = valid ? rowprob[bg_ + m0 + tid] : 0.f;
    }
    __syncthreads();

    int wave = tid >> 6, lane = tid & 63;
    int quad = lane >> 4, l16 = lane & 15;
    int wr = wave >> 1, wc = wave & 1;

    // staging (BK=64): each gload16 covers 8 rows x 64 k-elems; lane: r8=row, koff=k
    int r8   = lane >> 3;          // 0..7
    int koff = (lane & 7) * 8;     // 0..56
    const u16* ga[4]; const u16* gb[4];
    u16 *lA[4], *lB[4];
#pragma unroll
    for (int j = 0; j < 4; j++) {
        int arow = wave * 32 + j * 8 + r8;
        ga[j] = xb + (size_t)tks[arow] * DIM + koff;
        lA[j] = &As[(wave * 32 + j * 8) * 64];
        // B row n = wave*32 + j*8 + r8 ; chunk c=n>>4 ; is_up=c&1 ; f=f0+(c>>1)*16+(n&15)
        int c = wave * 2 + (j >> 1);
        const u16* src = (c & 1) ? wub : wgb;
        gb[j] = src + ((size_t)e * FF + f0 + (c >> 1) * 16 + (j & 1) * 8 + r8) * DIM + koff;
        lB[j] = &Bs[(wave * 32 + j * 8) * 64];
    }

    f32x4 acc[4][4] = {};

    for (int kk = 0; kk < DIM; kk += 64) {
#pragma unroll
        for (int j = 0; j < 4; j++) {
            gload16(ga[j] + kk, lA[j]);
            gload16(gb[j] + kk, lB[j]);
        }
        __syncthreads();
#pragma unroll
        for (int ks = 0; ks < 2; ks++) {
            bf16x8 a[4], b[4];
#pragma unroll
            for (int mi = 0; mi < 4; mi++)
                a[mi] = *(const bf16x8*)&As[(wr * 64 + mi * 16 + l16) * 64 + ks * 32 + quad * 8];
#pragma unroll
            for (int ni = 0; ni < 4; ni++)
                b[ni] = *(const bf16x8*)&Bs[(wc * 64 + ni * 16 + l16) * 64 + ks * 32 + quad * 8];
#pragma unroll
            for (int mi = 0; mi < 4; mi++)
#pragma unroll
                for (int ni = 0; ni < 4; ni++)
                    acc[mi][ni] = __builtin_amdgcn_mfma_f32_16x16x32_bf16(a[mi], b[ni], acc[mi][ni], 0, 0, 0);
        }
        __syncthreads();
    }

    // epilogue: n = wc*64 + ni*16 + l16 -> gate ni even, up ni odd; f = f0 + (wc*2 + ni>>1)*16 + l16
#pragma unroll
    for (int mi = 0; mi < 4; mi++) {
#pragma unroll
        for (int p = 0; p < 2; p++) {
            int f = f0 + (wc * 2 + p) * 16 + l16;
#pragma unroll
            for (int r = 0; r < 4; r++) {
                int m = wr * 64 + mi * 16 + quad * 4 + r;
                if (m0 + m < cg) {
                    float gv = acc[mi][p * 2][r], uv = acc[mi][p * 2 + 1][r];
                    float h = (gv / (1.f + __expf(-gv))) * uv * ps[m];
                    hidden[(size_t)(bg_ + m0 + m) * FF + f] = f2bf(h);
                }
            }
        }
    }
}

// ---------------- Down GEMM: 128 rows x 128 d, BK=64, scatter stores by slot ----------------
__launch_bounds__(256)
__global__ void down_kernel(const u16* __restrict__ hid, const u16* __restrict__ wdb,
                            const int* cnt, const int* base, const int* tile_g,
                            const int* tile_m0, const int* ntiles, const int* rowtok,
                            u16* __restrict__ out0, u16* __restrict__ out1) {
    int tile = blockIdx.x;
    if (tile >= *ntiles) return;
    int g = tile_g[tile], m0 = tile_m0[tile];
    int e = g >> 1, slot = g & 1;
    int d0 = blockIdx.y * 128;
    int cg = cnt[g], bg_ = base[g];

    __shared__ u16 As[128 * 64];
    __shared__ u16 Bs[128 * 64];
    __shared__ int tks[128];

    int tid = threadIdx.x;
    if (tid < 128) tks[tid] = ((m0 + tid) < cg) ? rowtok[bg_ + m0 + tid] : 0;
    __syncthreads();

    int wave = tid >> 6, lane = tid & 63;
    int quad = lane >> 4, l16 = lane & 15;
    int wr = wave >> 1, wc = wave & 1;

    int r8   = lane >> 3;
    int koff = (lane & 7) * 8;
    const u16* ga[4]; const u16* gb[4];
    u16 *lA[4], *lB[4];
#pragma unroll
    for (int j = 0; j < 4; j++) {
        ga[j] = hid + (size_t)(bg_ + m0 + wave * 32 + j * 8 + r8) * FF + koff;
        lA[j] = &As[(wave * 32 + j * 8) * 64];
        gb[j] = wdb + ((size_t)e * DIM + d0 + wave * 32 + j * 8 + r8) * FF + koff;
        lB[j] = &Bs[(wave * 32 + j * 8) * 64];
    }

    f32x4 acc[4][4] = {};

    for (int kk = 0; kk < FF; kk += 64) {
#pragma unroll
        for (int j = 0; j < 4; j++) {
            gload16(ga[j] + kk, lA[j]);
            gload16(gb[j] + kk, lB[j]);
        }
        __syncthreads();
#pragma unroll
        for (int ks = 0; ks < 2; ks++) {
            bf16x8 a[4], b[4];
#pragma unroll
            for (int mi = 0; mi < 4; mi++)
                a[mi] = *(const bf16x8*)&As[(wr * 64 + mi * 16 + l16) * 64 + ks * 32 + quad * 8];
#pragma unroll
            for (int ni = 0; ni < 4; ni++)
                b[ni] = *(const bf16x8*)&Bs[(wc * 64 + ni * 16 + l16) * 64 + ks * 32 + quad * 8];
#pragma unroll
            for (int mi = 0; mi < 4; mi++)
#pragma unroll
                for (int ni = 0; ni < 4; ni++)
                    acc[mi][ni] = __builtin_amdgcn_mfma_f32_16x16x32_bf16(a[mi], b[ni], acc[mi][ni], 0, 0, 0);
        }
        __syncthreads();
    }

    u16* outp = slot ? out1 : out0;
#pragma unroll
    for (int mi = 0; mi < 4; mi++) {
#pragma unroll
        for (int ni = 0; ni < 4; ni++) {
            int d = d0 + wc * 64 + ni * 16 + l16;
#pragma unroll
            for (int r = 0; r < 4; r++) {
                int m = wr * 64 + mi * 16 + quad * 4 + r;
                if (m0 + m < cg) {
                    outp[(size_t)tks[m] * DIM + d] = f2bf(acc[mi][ni][r]);
                }
            }
        }
    }
}

// ---------------- Combine: out = f32(o0) + f32(o1) ----------------
__global__ void combine_kernel(const u16* __restrict__ o0, const u16* __restrict__ o1,
                               float* __restrict__ out) {
    int i = blockIdx.x * blockDim.x + threadIdx.x;
    u16x8 a = *(const u16x8*)(o0 + (size_t)i * 8);
    u16x8 b = *(const u16x8*)(o1 + (size_t)i * 8);
    f32x4 r0, r1;
#pragma unroll
    for (int j = 0; j < 4; j++) {
        r0[j] = bf2f(a[j]) + bf2f(b[j]);
        r1[j] = bf2f(a[4 + j]) + bf2f(b[4 + j]);
    }
    *(f32x4*)(out + (size_t)i * 8) = r0;
    *(f32x4*)(out + (size_t)i * 8 + 4) = r1;
}

extern "C" void kernel_launch(void* const* d_in, const int* in_sizes, int n_in,
                              void* d_out, int out_size, void* d_ws, size_t ws_size,
                              hipStream_t stream) {
    const float* x  = (const float*)d_in[0];
    const float* wr = (const float*)d_in[1];
    const float* wg = (const float*)d_in[2];
    const float* wu = (const float*)d_in[3];
    const float* wd = (const float*)d_in[4];
    float* out = (float*)d_out;

    char* W = (char*)d_ws;
    int*   cnt     = (int*)(W + 0);
    int*   poscnt  = (int*)(W + 64);
    int*   base    = (int*)(W + 128);
    int*   ntiles  = (int*)(W + 192);
    int*   tile_g  = (int*)(W + 256);           // <=48
    int*   tile_m0 = (int*)(W + 512);           // <=48
    int*   rt_e    = (int*)(W + 1024);          // 4096 ints
    float* rt_p    = (float*)(W + 20480);
    int*   rowtok  = (int*)(W + 40960);
    float* rowprob = (float*)(W + 61440);
    u16*   hidden  = (u16*)(W + 81920);         // (4096+128) x 768 bf16 ~ 6.49 MB
    u16*   xb      = (u16*)(W + ((size_t)8  << 20));   // 8.39 MB
    u16*   wgb     = (u16*)(W + ((size_t)17 << 20));   // 25.2 MB (dead after gateup)
    u16*   wub     = (u16*)(W + ((size_t)43 << 20));   // 25.2 MB (dead after gateup)
    u16*   wdb     = (u16*)(W + ((size_t)69 << 20));   // 25.2 MB  (end ~94.4 MB)
    // out0/out1 overlap the wgb region (only written by down, after gateup finished)
    u16*   out0    = (u16*)(W + ((size_t)17 << 20));   // 8.39 MB
    u16*   out1    = (u16*)(W + ((size_t)26 << 20));   // 8.39 MB

    hipMemsetAsync(W, 0, 256, stream);   // cnt, poscnt, base, ntiles

    const int NW = NEXP * FF * DIM / 4;
    const int NX = T_TOK * DIM / 4;
    cvt4_kernel<<<dim3(1536, 4), 256, 0, stream>>>(x, xb, NX, wg, wgb, NW, wu, wub, NW, wd, wdb, NW);

    router_kernel<<<T_TOK, 64, 0, stream>>>(x, wr, cnt, rt_e, rt_p);
    scan_kernel<<<1, 64, 0, stream>>>(cnt, base, tile_g, tile_m0, ntiles);
    assign_kernel<<<8, 256, 0, stream>>>(rt_e, rt_p, base, poscnt, rowtok, rowprob);

    gateup_kernel<<<dim3(48, 12), 256, 0, stream>>>(xb, wgb, wub, cnt, base, tile_g, tile_m0,
                                                    ntiles, rowtok, rowprob, hidden);
    down_kernel<<<dim3(48, 16), 256, 0, stream>>>(hidden, wdb, cnt, base, tile_g, tile_m0,
                                                  ntiles, rowtok, out0, out1);
    combine_kernel<<<T_TOK * DIM / (256 * 8), 256, 0, stream>>>(out0, out1, out);
}

// Round 5
// 392.300 us; speedup vs baseline: 1.0513x; 1.0513x over previous
//
#include <hip/hip_runtime.h>

#define T_TOK 2048
#define DIM   2048
#define NEXP  8
#define FF    768
#define NGRP  16   // (expert, slot)

typedef unsigned short u16;
typedef unsigned int   u32;
typedef __bf16 bf16x8 __attribute__((ext_vector_type(8)));
typedef float  f32x4  __attribute__((ext_vector_type(4)));
typedef u16    u16x4  __attribute__((ext_vector_type(4)));
typedef u16    u16x8  __attribute__((ext_vector_type(8)));

__device__ __forceinline__ u16 f2bf(float f) {
    union { u32 i; float f; } v; v.f = f;
    u32 r = v.i + 0x7FFF + ((v.i >> 16) & 1);   // round-to-nearest-even
    return (u16)(r >> 16);
}
__device__ __forceinline__ float bf2f(u16 u) {
    union { u32 i; float f; } v; v.i = ((u32)u) << 16; return v.f;
}

// ---------------- fused fp32 -> bf16 bulk convert (4 tensors) ----------------
__global__ void cvt4_kernel(const float* __restrict__ s0, u16* __restrict__ d0, int n0,
                            const float* __restrict__ s1, u16* __restrict__ d1, int n1,
                            const float* __restrict__ s2, u16* __restrict__ d2, int n2,
                            const float* __restrict__ s3, u16* __restrict__ d3, int n3) {
    const float* s; u16* d; int n4;
    switch (blockIdx.y) {
        case 0: s = s0; d = d0; n4 = n0; break;
        case 1: s = s1; d = d1; n4 = n1; break;
        case 2: s = s2; d = d2; n4 = n2; break;
        default: s = s3; d = d3; n4 = n3; break;
    }
    int i = blockIdx.x * blockDim.x + threadIdx.x;
    int st = gridDim.x * blockDim.x;
    for (; i < n4; i += st) {
        f32x4 v = ((const f32x4*)s)[i];
        u16x4 o;
#pragma unroll
        for (int j = 0; j < 4; j++) o[j] = f2bf(v[j]);
        ((u16x4*)d)[i] = o;
    }
}

// ---------------- Router: scores, top-2, softmax, group counts ----------------
__global__ void router_kernel(const float* __restrict__ x, const float* __restrict__ wr,
                              int* cnt, int* rt_e, float* rt_p) {
    int t = blockIdx.x;
    int lane = threadIdx.x;
    float xv[32];
#pragma unroll
    for (int i = 0; i < 32; i++) xv[i] = x[(size_t)t * DIM + i * 64 + lane];
    float s[NEXP];
#pragma unroll
    for (int e = 0; e < NEXP; e++) {
        float acc = 0.f;
#pragma unroll
        for (int i = 0; i < 32; i++) acc += xv[i] * wr[(size_t)e * DIM + i * 64 + lane];
        for (int off = 32; off; off >>= 1) acc += __shfl_xor(acc, off);
        s[e] = acc;
    }
    if (lane == 0) {
        int bi = 0; float bv = s[0];
        for (int e = 1; e < NEXP; e++) if (s[e] > bv) { bv = s[e]; bi = e; }
        float sv = -1e30f; int si = 0;
        for (int e = 0; e < NEXP; e++) { if (e == bi) continue; if (s[e] > sv) { sv = s[e]; si = e; } }
        float p0 = 1.f / (1.f + __expf(sv - bv));
        float p1 = 1.f - p0;
        rt_e[t * 2 + 0] = bi; rt_e[t * 2 + 1] = si;
        rt_p[t * 2 + 0] = p0; rt_p[t * 2 + 1] = p1;
        atomicAdd(&cnt[bi * 2 + 0], 1);
        atomicAdd(&cnt[si * 2 + 1], 1);
    }
}

// ---------------- Scan: bases + 128-row tile worklist ----------------
__global__ void scan_kernel(const int* cnt, int* base, int* tile_g, int* tile_m0, int* ntiles) {
    if (threadIdx.x == 0 && blockIdx.x == 0) {
        int off = 0, nt = 0;
        for (int g = 0; g < NGRP; g++) {
            base[g] = off;
            int c = cnt[g];
            for (int m0 = 0; m0 < c; m0 += 128) { tile_g[nt] = g; tile_m0[nt] = m0; nt++; }
            off += c;
        }
        *ntiles = nt;
    }
}

// ---------------- Assign: compact row -> (token, prob) ----------------
__global__ void assign_kernel(const int* rt_e, const float* rt_p, const int* base,
                              int* poscnt, int* rowtok, float* rowprob) {
    int t = blockIdx.x * blockDim.x + threadIdx.x;
    if (t >= T_TOK) return;
    for (int k = 0; k < 2; k++) {
        int g = rt_e[t * 2 + k] * 2 + k;
        int pos = atomicAdd(&poscnt[g], 1);
        int row = base[g] + pos;
        rowtok[row] = t;
        rowprob[row] = rt_p[t * 2 + k];
    }
}

// ---- Gate/Up GEMM + SiLU: 128 rows x 64 f (N=128 G|U interleaved), BK=32, reg-prefetch ----
__launch_bounds__(256)
__global__ void gateup_kernel(const u16* __restrict__ xb, const u16* __restrict__ wgb,
                              const u16* __restrict__ wub,
                              const int* cnt, const int* base, const int* tile_g,
                              const int* tile_m0, const int* ntiles,
                              const int* rowtok, const float* rowprob,
                              u16* __restrict__ hidden) {
    int tile = blockIdx.x;
    if (tile >= *ntiles) return;
    int g = tile_g[tile], m0 = tile_m0[tile];
    int e = g >> 1;
    int f0 = blockIdx.y * 64;
    int cg = cnt[g], bg_ = base[g];

    __shared__ u16 As[128 * 32];
    __shared__ u16 Bs[128 * 32];
    __shared__ int   tks[128];
    __shared__ float ps[128];

    int tid = threadIdx.x;
    if (tid < 128) {
        int valid = (m0 + tid) < cg;
        tks[tid] = valid ? rowtok[bg_ + m0 + tid] : 0;
        ps[tid]  = valid ? rowprob[bg_ + m0 + tid] : 0.f;
    }
    __syncthreads();

    int wave = tid >> 6, lane = tid & 63;
    int quad = lane >> 4, l16 = lane & 15;
    int wr = wave >> 1, wc = wave & 1;

    // staging: wave w stages A rows [w*32, w*32+32) and B rows [w*32, w*32+32)
    int r4   = lane >> 2;          // 0..15
    int koff = (lane & 3) * 8;     // 0,8,16,24
    const u16* ga0 = xb + (size_t)tks[wave * 32 + r4] * DIM + koff;
    const u16* ga1 = xb + (size_t)tks[wave * 32 + 16 + r4] * DIM + koff;
    const u16* gb0 = wgb + ((size_t)e * FF + f0 + wave * 16 + r4) * DIM + koff;  // gate
    const u16* gb1 = wub + ((size_t)e * FF + f0 + wave * 16 + r4) * DIM + koff;  // up
    u16* uA0 = &As[(wave * 32 + r4) * 32 + koff];
    u16* uA1 = &As[(wave * 32 + 16 + r4) * 32 + koff];
    u16* uB0 = &Bs[(wave * 32 + r4) * 32 + koff];
    u16* uB1 = &Bs[(wave * 32 + 16 + r4) * 32 + koff];

    f32x4 acc[4][4] = {};

    u16x8 pa0 = *(const u16x8*)ga0, pa1 = *(const u16x8*)ga1;
    u16x8 pb0 = *(const u16x8*)gb0, pb1 = *(const u16x8*)gb1;

    for (int kk = 0; kk < DIM; kk += 32) {
        __syncthreads();                 // prior iter's LDS reads complete
        *(u16x8*)uA0 = pa0; *(u16x8*)uA1 = pa1;
        *(u16x8*)uB0 = pb0; *(u16x8*)uB1 = pb1;
        __syncthreads();                 // writes visible
        if (kk + 32 < DIM) {             // prefetch next slab; latency overlaps MFMAs below
            pa0 = *(const u16x8*)(ga0 + kk + 32);
            pa1 = *(const u16x8*)(ga1 + kk + 32);
            pb0 = *(const u16x8*)(gb0 + kk + 32);
            pb1 = *(const u16x8*)(gb1 + kk + 32);
        }
        bf16x8 a[4], b[4];
#pragma unroll
        for (int mi = 0; mi < 4; mi++)
            a[mi] = *(const bf16x8*)&As[(wr * 64 + mi * 16 + l16) * 32 + quad * 8];
#pragma unroll
        for (int ni = 0; ni < 4; ni++)
            b[ni] = *(const bf16x8*)&Bs[(wc * 64 + ni * 16 + l16) * 32 + quad * 8];
#pragma unroll
        for (int mi = 0; mi < 4; mi++)
#pragma unroll
            for (int ni = 0; ni < 4; ni++)
                acc[mi][ni] = __builtin_amdgcn_mfma_f32_16x16x32_bf16(a[mi], b[ni], acc[mi][ni], 0, 0, 0);
    }

    // epilogue: B row n = wc*64 + ni*16 + l16; chunk c=n>>4; gate: c even; f = f0+(c>>1)*16+l16
#pragma unroll
    for (int mi = 0; mi < 4; mi++) {
#pragma unroll
        for (int p = 0; p < 2; p++) {
            int f = f0 + (wc * 2 + p) * 16 + l16;
#pragma unroll
            for (int r = 0; r < 4; r++) {
                int m = wr * 64 + mi * 16 + quad * 4 + r;
                if (m0 + m < cg) {
                    float gv = acc[mi][p * 2][r], uv = acc[mi][p * 2 + 1][r];
                    float h = (gv / (1.f + __expf(-gv))) * uv * ps[m];
                    hidden[(size_t)(bg_ + m0 + m) * FF + f] = f2bf(h);
                }
            }
        }
    }
}

// ---- Down GEMM: 128 rows x 128 d, BK=32, reg-prefetch, slot-scatter stores ----
__launch_bounds__(256)
__global__ void down_kernel(const u16* __restrict__ hid, const u16* __restrict__ wdb,
                            const int* cnt, const int* base, const int* tile_g,
                            const int* tile_m0, const int* ntiles, const int* rowtok,
                            u16* __restrict__ out0, u16* __restrict__ out1) {
    int tile = blockIdx.x;
    if (tile >= *ntiles) return;
    int g = tile_g[tile], m0 = tile_m0[tile];
    int e = g >> 1, slot = g & 1;
    int d0 = blockIdx.y * 128;
    int cg = cnt[g], bg_ = base[g];

    __shared__ u16 As[128 * 32];
    __shared__ u16 Bs[128 * 32];
    __shared__ int tks[128];

    int tid = threadIdx.x;
    if (tid < 128) tks[tid] = ((m0 + tid) < cg) ? rowtok[bg_ + m0 + tid] : 0;
    __syncthreads();

    int wave = tid >> 6, lane = tid & 63;
    int quad = lane >> 4, l16 = lane & 15;
    int wr = wave >> 1, wc = wave & 1;

    int r4   = lane >> 2;
    int koff = (lane & 3) * 8;
    const u16* ga0 = hid + (size_t)(bg_ + m0 + wave * 32 + r4) * FF + koff;
    const u16* ga1 = hid + (size_t)(bg_ + m0 + wave * 32 + 16 + r4) * FF + koff;
    const u16* gb0 = wdb + ((size_t)e * DIM + d0 + wave * 32 + r4) * FF + koff;
    const u16* gb1 = wdb + ((size_t)e * DIM + d0 + wave * 32 + 16 + r4) * FF + koff;
    u16* uA0 = &As[(wave * 32 + r4) * 32 + koff];
    u16* uA1 = &As[(wave * 32 + 16 + r4) * 32 + koff];
    u16* uB0 = &Bs[(wave * 32 + r4) * 32 + koff];
    u16* uB1 = &Bs[(wave * 32 + 16 + r4) * 32 + koff];

    f32x4 acc[4][4] = {};

    u16x8 pa0 = *(const u16x8*)ga0, pa1 = *(const u16x8*)ga1;
    u16x8 pb0 = *(const u16x8*)gb0, pb1 = *(const u16x8*)gb1;

    for (int kk = 0; kk < FF; kk += 32) {
        __syncthreads();
        *(u16x8*)uA0 = pa0; *(u16x8*)uA1 = pa1;
        *(u16x8*)uB0 = pb0; *(u16x8*)uB1 = pb1;
        __syncthreads();
        if (kk + 32 < FF) {
            pa0 = *(const u16x8*)(ga0 + kk + 32);
            pa1 = *(const u16x8*)(ga1 + kk + 32);
            pb0 = *(const u16x8*)(gb0 + kk + 32);
            pb1 = *(const u16x8*)(gb1 + kk + 32);
        }
        bf16x8 a[4], b[4];
#pragma unroll
        for (int mi = 0; mi < 4; mi++)
            a[mi] = *(const bf16x8*)&As[(wr * 64 + mi * 16 + l16) * 32 + quad * 8];
#pragma unroll
        for (int ni = 0; ni < 4; ni++)
            b[ni] = *(const bf16x8*)&Bs[(wc * 64 + ni * 16 + l16) * 32 + quad * 8];
#pragma unroll
        for (int mi = 0; mi < 4; mi++)
#pragma unroll
            for (int ni = 0; ni < 4; ni++)
                acc[mi][ni] = __builtin_amdgcn_mfma_f32_16x16x32_bf16(a[mi], b[ni], acc[mi][ni], 0, 0, 0);
    }

    u16* outp = slot ? out1 : out0;
#pragma unroll
    for (int mi = 0; mi < 4; mi++) {
#pragma unroll
        for (int ni = 0; ni < 4; ni++) {
            int d = d0 + wc * 64 + ni * 16 + l16;
#pragma unroll
            for (int r = 0; r < 4; r++) {
                int m = wr * 64 + mi * 16 + quad * 4 + r;
                if (m0 + m < cg) {
                    outp[(size_t)tks[m] * DIM + d] = f2bf(acc[mi][ni][r]);
                }
            }
        }
    }
}

// ---------------- Combine: out = f32(o0) + f32(o1) ----------------
__global__ void combine_kernel(const u16* __restrict__ o0, const u16* __restrict__ o1,
                               float* __restrict__ out) {
    int i = blockIdx.x * blockDim.x + threadIdx.x;
    u16x8 a = *(const u16x8*)(o0 + (size_t)i * 8);
    u16x8 b = *(const u16x8*)(o1 + (size_t)i * 8);
    f32x4 r0, r1;
#pragma unroll
    for (int j = 0; j < 4; j++) {
        r0[j] = bf2f(a[j]) + bf2f(b[j]);
        r1[j] = bf2f(a[4 + j]) + bf2f(b[4 + j]);
    }
    *(f32x4*)(out + (size_t)i * 8) = r0;
    *(f32x4*)(out + (size_t)i * 8 + 4) = r1;
}

extern "C" void kernel_launch(void* const* d_in, const int* in_sizes, int n_in,
                              void* d_out, int out_size, void* d_ws, size_t ws_size,
                              hipStream_t stream) {
    const float* x  = (const float*)d_in[0];
    const float* wr = (const float*)d_in[1];
    const float* wg = (const float*)d_in[2];
    const float* wu = (const float*)d_in[3];
    const float* wd = (const float*)d_in[4];
    float* out = (float*)d_out;

    char* W = (char*)d_ws;
    int*   cnt     = (int*)(W + 0);
    int*   poscnt  = (int*)(W + 64);
    int*   base    = (int*)(W + 128);
    int*   ntiles  = (int*)(W + 192);
    int*   tile_g  = (int*)(W + 256);           // <=48
    int*   tile_m0 = (int*)(W + 512);           // <=48
    int*   rt_e    = (int*)(W + 1024);          // 4096 ints
    float* rt_p    = (float*)(W + 20480);
    int*   rowtok  = (int*)(W + 40960);
    float* rowprob = (float*)(W + 61440);
    u16*   hidden  = (u16*)(W + 81920);         // (4096+128) x 768 bf16 ~ 6.49 MB
    u16*   xb      = (u16*)(W + ((size_t)8  << 20));   // 8.39 MB
    u16*   wgb     = (u16*)(W + ((size_t)17 << 20));   // 25.2 MB (dead after gateup)
    u16*   wub     = (u16*)(W + ((size_t)43 << 20));   // 25.2 MB (dead after gateup)
    u16*   wdb     = (u16*)(W + ((size_t)69 << 20));   // 25.2 MB  (end ~94.4 MB)
    // out0/out1 overlap the wgb region (only written by down, after gateup finished)
    u16*   out0    = (u16*)(W + ((size_t)17 << 20));   // 8.39 MB
    u16*   out1    = (u16*)(W + ((size_t)26 << 20));   // 8.39 MB

    hipMemsetAsync(W, 0, 256, stream);   // cnt, poscnt, base, ntiles

    const int NW = NEXP * FF * DIM / 4;
    const int NX = T_TOK * DIM / 4;
    cvt4_kernel<<<dim3(1536, 4), 256, 0, stream>>>(x, xb, NX, wg, wgb, NW, wu, wub, NW, wd, wdb, NW);

    router_kernel<<<T_TOK, 64, 0, stream>>>(x, wr, cnt, rt_e, rt_p);
    scan_kernel<<<1, 64, 0, stream>>>(cnt, base, tile_g, tile_m0, ntiles);
    assign_kernel<<<8, 256, 0, stream>>>(rt_e, rt_p, base, poscnt, rowtok, rowprob);

    gateup_kernel<<<dim3(48, 12), 256, 0, stream>>>(xb, wgb, wub, cnt, base, tile_g, tile_m0,
                                                    ntiles, rowtok, rowprob, hidden);
    down_kernel<<<dim3(48, 16), 256, 0, stream>>>(hidden, wdb, cnt, base, tile_g, tile_m0,
                                                  ntiles, rowtok, out0, out1);
    combine_kernel<<<T_TOK * DIM / (256 * 8), 256, 0, stream>>>(out0, out1, out);
}

// Round 6
// 385.378 us; speedup vs baseline: 1.0702x; 1.0180x over previous
//
#include <hip/hip_runtime.h>

#define T_TOK 2048
#define DIM   2048
#define NEXP  8
#define FF    768
#define NGRP  16   // (expert, slot)

typedef unsigned short u16;
typedef unsigned int   u32;
typedef __bf16 bf16x8 __attribute__((ext_vector_type(8)));
typedef float  f32x4  __attribute__((ext_vector_type(4)));
typedef u16    u16x4  __attribute__((ext_vector_type(4)));
typedef u16    u16x8  __attribute__((ext_vector_type(8)));

#define AS1 __attribute__((address_space(1)))
#define AS3 __attribute__((address_space(3)))

__device__ __forceinline__ u16 f2bf(float f) {
    union { u32 i; float f; } v; v.f = f;
    u32 r = v.i + 0x7FFF + ((v.i >> 16) & 1);   // round-to-nearest-even
    return (u16)(r >> 16);
}
__device__ __forceinline__ float bf2f(u16 u) {
    union { u32 i; float f; } v; v.i = ((u32)u) << 16; return v.f;
}

// async global->LDS, 16B per lane; LDS dest = wave-uniform base + lane*16
__device__ __forceinline__ void gload16(const u16* g, u16* l) {
    __builtin_amdgcn_global_load_lds((const AS1 u32*)g, (AS3 u32*)l, 16, 0, 0);
}

// ---------------- fp32 -> bf16 bulk convert (3 weight tensors) ----------------
__global__ void cvt3_kernel(const float* __restrict__ s0, u16* __restrict__ d0,
                            const float* __restrict__ s1, u16* __restrict__ d1,
                            const float* __restrict__ s2, u16* __restrict__ d2, int n4) {
    const float* s; u16* d;
    switch (blockIdx.y) {
        case 0: s = s0; d = d0; break;
        case 1: s = s1; d = d1; break;
        default: s = s2; d = d2; break;
    }
    int i = blockIdx.x * blockDim.x + threadIdx.x;
    int st = gridDim.x * blockDim.x;
    for (; i < n4; i += st) {
        f32x4 v = ((const f32x4*)s)[i];
        u16x4 o;
#pragma unroll
        for (int j = 0; j < 4; j++) o[j] = f2bf(v[j]);
        ((u16x4*)d)[i] = o;
    }
}

// ------- Router: scores, top-2, softmax, counts; also emits xb = bf16(x) -------
__global__ void router_kernel(const float* __restrict__ x, const float* __restrict__ wr,
                              int* cnt, int* rt_e, float* rt_p, u16* __restrict__ xb) {
    int wave = threadIdx.x >> 6, lane = threadIdx.x & 63;
    int t = blockIdx.x * 4 + wave;
    float xv[32];
#pragma unroll
    for (int i = 0; i < 32; i++) xv[i] = x[(size_t)t * DIM + i * 64 + lane];
#pragma unroll
    for (int i = 0; i < 32; i++) xb[(size_t)t * DIM + i * 64 + lane] = f2bf(xv[i]);
    float s[NEXP];
#pragma unroll
    for (int e = 0; e < NEXP; e++) {
        float acc = 0.f;
#pragma unroll
        for (int i = 0; i < 32; i++) acc += xv[i] * wr[(size_t)e * DIM + i * 64 + lane];
        for (int off = 32; off; off >>= 1) acc += __shfl_xor(acc, off);
        s[e] = acc;
    }
    if (lane == 0) {
        int bi = 0; float bv = s[0];
        for (int e = 1; e < NEXP; e++) if (s[e] > bv) { bv = s[e]; bi = e; }
        float sv = -1e30f; int si = 0;
        for (int e = 0; e < NEXP; e++) { if (e == bi) continue; if (s[e] > sv) { sv = s[e]; si = e; } }
        float p0 = 1.f / (1.f + __expf(sv - bv));
        float p1 = 1.f - p0;
        rt_e[t * 2 + 0] = bi; rt_e[t * 2 + 1] = si;
        rt_p[t * 2 + 0] = p0; rt_p[t * 2 + 1] = p1;
        atomicAdd(&cnt[bi * 2 + 0], 1);
        atomicAdd(&cnt[si * 2 + 1], 1);
    }
}

// ---------------- Scan (one wave): bases + 128-row tile worklist ----------------
__global__ void scan_kernel(const int* cnt, int* base, int* tile_g, int* tile_m0, int* ntiles) {
    int lane = threadIdx.x;
    int c = (lane < NGRP) ? cnt[lane] : 0;
    int nt_g = (c + 127) >> 7;
    int pre = 0, tpre = 0;
    for (int i = 0; i < NGRP; i++) {
        int ci = __shfl(c, i), ti = __shfl(nt_g, i);
        if (i < lane) { pre += ci; tpre += ti; }
    }
    if (lane < NGRP) {
        base[lane] = pre;
        for (int j = 0; j < nt_g; j++) { tile_g[tpre + j] = lane; tile_m0[tpre + j] = j * 128; }
        if (lane == NGRP - 1) *ntiles = tpre + nt_g;
    }
}

// ---------------- Assign: compact row -> (token, prob) ----------------
__global__ void assign_kernel(const int* rt_e, const float* rt_p, const int* base,
                              int* poscnt, int* rowtok, float* rowprob) {
    int t = blockIdx.x * blockDim.x + threadIdx.x;
    if (t >= T_TOK) return;
    for (int k = 0; k < 2; k++) {
        int g = rt_e[t * 2 + k] * 2 + k;
        int pos = atomicAdd(&poscnt[g], 1);
        int row = base[g] + pos;
        rowtok[row] = t;
        rowprob[row] = rt_p[t * 2 + k];
    }
}

// ---- Gate/Up GEMM + SiLU: 128 rows x 32 f (N=64: gate|up 16-col frags), BK=32, gload16 ----
__launch_bounds__(256)
__global__ void gateup_kernel(const u16* __restrict__ xb, const u16* __restrict__ wgb,
                              const u16* __restrict__ wub,
                              const int* cnt, const int* base, const int* tile_g,
                              const int* tile_m0, const int* ntiles,
                              const int* rowtok, const float* rowprob,
                              u16* __restrict__ hidden) {
    int tile = blockIdx.x;
    if (tile >= *ntiles) return;
    int g = tile_g[tile], m0 = tile_m0[tile];
    int e = g >> 1;
    int f0 = blockIdx.y * 32;
    int cg = cnt[g], bg_ = base[g];

    __shared__ u16 As[128 * 32];   // 8 KB
    __shared__ u16 Bs[64 * 32];    // 4 KB
    __shared__ int   tks[128];
    __shared__ float ps[128];

    int tid = threadIdx.x;
    if (tid < 128) {
        int valid = (m0 + tid) < cg;
        tks[tid] = valid ? rowtok[bg_ + m0 + tid] : 0;
        ps[tid]  = valid ? rowprob[bg_ + m0 + tid] : 0.f;
    }
    __syncthreads();

    int wave = tid >> 6, lane = tid & 63;
    int quad = lane >> 4, l16 = lane & 15;
    int wr = wave >> 1, wc = wave & 1;

    int r4   = lane >> 2;          // 0..15
    int koff = (lane & 3) * 8;     // 0,8,16,24
    // A: wave stages rows [wave*32, +32)
    const u16* ga0 = xb + (size_t)tks[wave * 32 + r4] * DIM + koff;
    const u16* ga1 = xb + (size_t)tks[wave * 32 + 16 + r4] * DIM + koff;
    u16* lA0 = &As[(wave * 32) * 32];
    u16* lA1 = &As[(wave * 32 + 16) * 32];
    // B LDS row n: wc=n>>5, frag=(n>>4)&1 (0=gate,1=up), f=f0+wc*16+(n&15)
    // wave stages rows [wave*16, +16): frag=wave&1, f=f0+(wave>>1)*16+r4
    const u16* bsrc = (wave & 1) ? wub : wgb;
    const u16* gb = bsrc + ((size_t)e * FF + f0 + (wave >> 1) * 16 + r4) * DIM + koff;
    u16* lB = &Bs[(wave * 16) * 32];

    f32x4 acc[4][2] = {};

    for (int kk = 0; kk < DIM; kk += 32) {
        gload16(ga0 + kk, lA0);
        gload16(ga1 + kk, lA1);
        gload16(gb + kk, lB);
        __syncthreads();
        bf16x8 a[4], b[2];
#pragma unroll
        for (int mi = 0; mi < 4; mi++)
            a[mi] = *(const bf16x8*)&As[(wr * 64 + mi * 16 + l16) * 32 + quad * 8];
#pragma unroll
        for (int ni = 0; ni < 2; ni++)
            b[ni] = *(const bf16x8*)&Bs[(wc * 32 + ni * 16 + l16) * 32 + quad * 8];
#pragma unroll
        for (int mi = 0; mi < 4; mi++)
#pragma unroll
            for (int ni = 0; ni < 2; ni++)
                acc[mi][ni] = __builtin_amdgcn_mfma_f32_16x16x32_bf16(a[mi], b[ni], acc[mi][ni], 0, 0, 0);
        __syncthreads();
    }

    // epilogue: gate = acc[mi][0], up = acc[mi][1]; f = f0 + wc*16 + l16
    int f = f0 + wc * 16 + l16;
#pragma unroll
    for (int mi = 0; mi < 4; mi++) {
#pragma unroll
        for (int r = 0; r < 4; r++) {
            int m = wr * 64 + mi * 16 + quad * 4 + r;
            if (m0 + m < cg) {
                float gv = acc[mi][0][r], uv = acc[mi][1][r];
                float h = (gv / (1.f + __expf(-gv))) * uv * ps[m];
                hidden[(size_t)(bg_ + m0 + m) * FF + f] = f2bf(h);
            }
        }
    }
}

// ---- Down GEMM: 128 rows x 64 d, BK=32, gload16, slot-scatter stores ----
__launch_bounds__(256)
__global__ void down_kernel(const u16* __restrict__ hid, const u16* __restrict__ wdb,
                            const int* cnt, const int* base, const int* tile_g,
                            const int* tile_m0, const int* ntiles, const int* rowtok,
                            u16* __restrict__ out0, u16* __restrict__ out1) {
    int tile = blockIdx.x;
    if (tile >= *ntiles) return;
    int g = tile_g[tile], m0 = tile_m0[tile];
    int e = g >> 1, slot = g & 1;
    int d0 = blockIdx.y * 64;
    int cg = cnt[g], bg_ = base[g];

    __shared__ u16 As[128 * 32];
    __shared__ u16 Bs[64 * 32];
    __shared__ int tks[128];

    int tid = threadIdx.x;
    if (tid < 128) tks[tid] = ((m0 + tid) < cg) ? rowtok[bg_ + m0 + tid] : 0;
    __syncthreads();

    int wave = tid >> 6, lane = tid & 63;
    int quad = lane >> 4, l16 = lane & 15;
    int wr = wave >> 1, wc = wave & 1;

    int r4   = lane >> 2;
    int koff = (lane & 3) * 8;
    const u16* ga0 = hid + (size_t)(bg_ + m0 + wave * 32 + r4) * FF + koff;
    const u16* ga1 = hid + (size_t)(bg_ + m0 + wave * 32 + 16 + r4) * FF + koff;
    u16* lA0 = &As[(wave * 32) * 32];
    u16* lA1 = &As[(wave * 32 + 16) * 32];
    const u16* gb = wdb + ((size_t)e * DIM + d0 + wave * 16 + r4) * FF + koff;
    u16* lB = &Bs[(wave * 16) * 32];

    f32x4 acc[4][2] = {};

    for (int kk = 0; kk < FF; kk += 32) {
        gload16(ga0 + kk, lA0);
        gload16(ga1 + kk, lA1);
        gload16(gb + kk, lB);
        __syncthreads();
        bf16x8 a[4], b[2];
#pragma unroll
        for (int mi = 0; mi < 4; mi++)
            a[mi] = *(const bf16x8*)&As[(wr * 64 + mi * 16 + l16) * 32 + quad * 8];
#pragma unroll
        for (int ni = 0; ni < 2; ni++)
            b[ni] = *(const bf16x8*)&Bs[(wc * 32 + ni * 16 + l16) * 32 + quad * 8];
#pragma unroll
        for (int mi = 0; mi < 4; mi++)
#pragma unroll
            for (int ni = 0; ni < 2; ni++)
                acc[mi][ni] = __builtin_amdgcn_mfma_f32_16x16x32_bf16(a[mi], b[ni], acc[mi][ni], 0, 0, 0);
        __syncthreads();
    }

    u16* outp = slot ? out1 : out0;
#pragma unroll
    for (int mi = 0; mi < 4; mi++) {
#pragma unroll
        for (int ni = 0; ni < 2; ni++) {
            int d = d0 + wc * 32 + ni * 16 + l16;
#pragma unroll
            for (int r = 0; r < 4; r++) {
                int m = wr * 64 + mi * 16 + quad * 4 + r;
                if (m0 + m < cg) {
                    outp[(size_t)tks[m] * DIM + d] = f2bf(acc[mi][ni][r]);
                }
            }
        }
    }
}

// ---------------- Combine: out = f32(o0) + f32(o1) ----------------
__global__ void combine_kernel(const u16* __restrict__ o0, const u16* __restrict__ o1,
                               float* __restrict__ out) {
    int i = blockIdx.x * blockDim.x + threadIdx.x;
    u16x8 a = *(const u16x8*)(o0 + (size_t)i * 8);
    u16x8 b = *(const u16x8*)(o1 + (size_t)i * 8);
    f32x4 r0, r1;
#pragma unroll
    for (int j = 0; j < 4; j++) {
        r0[j] = bf2f(a[j]) + bf2f(b[j]);
        r1[j] = bf2f(a[4 + j]) + bf2f(b[4 + j]);
    }
    *(f32x4*)(out + (size_t)i * 8) = r0;
    *(f32x4*)(out + (size_t)i * 8 + 4) = r1;
}

extern "C" void kernel_launch(void* const* d_in, const int* in_sizes, int n_in,
                              void* d_out, int out_size, void* d_ws, size_t ws_size,
                              hipStream_t stream) {
    const float* x  = (const float*)d_in[0];
    const float* wr = (const float*)d_in[1];
    const float* wg = (const float*)d_in[2];
    const float* wu = (const float*)d_in[3];
    const float* wd = (const float*)d_in[4];
    float* out = (float*)d_out;

    char* W = (char*)d_ws;
    int*   cnt     = (int*)(W + 0);
    int*   poscnt  = (int*)(W + 64);
    int*   base    = (int*)(W + 128);
    int*   ntiles  = (int*)(W + 192);
    int*   tile_g  = (int*)(W + 256);           // <=48
    int*   tile_m0 = (int*)(W + 512);           // <=48
    int*   rt_e    = (int*)(W + 1024);          // 4096 ints
    float* rt_p    = (float*)(W + 20480);
    int*   rowtok  = (int*)(W + 40960);
    float* rowprob = (float*)(W + 61440);
    u16*   hidden  = (u16*)(W + 81920);         // (4096+128) x 768 bf16 ~ 6.49 MB
    u16*   xb      = (u16*)(W + ((size_t)8  << 20));   // 8.39 MB
    u16*   wgb     = (u16*)(W + ((size_t)17 << 20));   // 25.2 MB (dead after gateup)
    u16*   wub     = (u16*)(W + ((size_t)43 << 20));   // 25.2 MB (dead after gateup)
    u16*   wdb     = (u16*)(W + ((size_t)69 << 20));   // 25.2 MB  (end ~94.4 MB)
    // out0/out1 overlap the wgb region (only written by down, after gateup finished)
    u16*   out0    = (u16*)(W + ((size_t)17 << 20));   // 8.39 MB
    u16*   out1    = (u16*)(W + ((size_t)26 << 20));   // 8.39 MB

    hipMemsetAsync(W, 0, 256, stream);   // cnt, poscnt, base, ntiles

    const int NW = NEXP * FF * DIM / 4;
    cvt3_kernel<<<dim3(1536, 3), 256, 0, stream>>>(wg, wgb, wu, wub, wd, wdb, NW);

    router_kernel<<<T_TOK / 4, 256, 0, stream>>>(x, wr, cnt, rt_e, rt_p, xb);
    scan_kernel<<<1, 64, 0, stream>>>(cnt, base, tile_g, tile_m0, ntiles);
    assign_kernel<<<8, 256, 0, stream>>>(rt_e, rt_p, base, poscnt, rowtok, rowprob);

    gateup_kernel<<<dim3(48, 24), 256, 0, stream>>>(xb, wgb, wub, cnt, base, tile_g, tile_m0,
                                                    ntiles, rowtok, rowprob, hidden);
    down_kernel<<<dim3(48, 32), 256, 0, stream>>>(hidden, wdb, cnt, base, tile_g, tile_m0,
                                                  ntiles, rowtok, out0, out1);
    combine_kernel<<<T_TOK * DIM / (256 * 8), 256, 0, stream>>>(out0, out1, out);
}